// Round 2
// baseline (181.011 us; speedup 1.0000x reference)
//
#include <hip/hip_runtime.h>
#include <cstdint>
#include <cstddef>

// Problem: B=8,S=2048,E=512,FFN=2048,Q=8  ->  M=16384, K=2048, N=512.
// Fused act(z@w1^T+b1,relu,bf16) + GEMM2. Round-2 structure:
//   BM=64, BN=256, 256 thr (4 waves, wave tile 64x64), grid=512 = 2 blocks/CU.
//   Double-buffered As/Bs/w1s, ONE __syncthreads per K-step: stage(next) +
//   act(next) + MFMA(cur) share the inter-barrier window, so staging latency
//   and act-VALU hide under MFMA (and under the sibling block on the same CU).

typedef __attribute__((ext_vector_type(8))) short s16x8;
typedef __attribute__((ext_vector_type(4))) float f32x4;

// round-to-nearest-even fp32 -> bf16 (identical to passing rounds)
__device__ __forceinline__ unsigned short f2bf(float f) {
  unsigned int u = __float_as_uint(f);
  unsigned int r = u + 0x7fffu + ((u >> 16) & 1u);
  return (unsigned short)(r >> 16);
}

__device__ __forceinline__ void async_copy16(const void* g, void* l) {
  __builtin_amdgcn_global_load_lds(
      (const __attribute__((address_space(1))) void*)(uintptr_t)g,
      (__attribute__((address_space(3))) void*)(unsigned int)(uintptr_t)l,
      16, 0, 0);
}

// ---------------------------------------------------------------------------
// Kernel 1: w2 (fp32 [512][2048]) -> bf16 same layout (one-time, ~2 us)
// ---------------------------------------------------------------------------
__global__ __launch_bounds__(256) void k_w2(const float* __restrict__ w2,
                                            unsigned short* __restrict__ w2b) {
  size_t i = ((size_t)blockIdx.x * 256 + threadIdx.x) * 4;
  float4 v = *(const float4*)(w2 + i);
  uint2 p;
  p.x = f2bf(v.x) | ((unsigned)f2bf(v.y) << 16);
  p.y = f2bf(v.z) | ((unsigned)f2bf(v.w) << 16);
  *(uint2*)(w2b + i) = p;
}

// ---------------------------------------------------------------------------
// Kernel 2 (fused): C[m][n] = sum_k relu(z[m]·w1[k]+b1[k]) * w2b[n][k] + b2[n]
// ---------------------------------------------------------------------------
__global__ __launch_bounds__(256, 2) void k_fused(
    const float* __restrict__ x, const float* __restrict__ ry,
    const float* __restrict__ w1, const float* __restrict__ b1,
    const unsigned short* __restrict__ w2b, const float* __restrict__ b2,
    float* __restrict__ C) {
  __shared__ unsigned short As[2][64 * 32];   // 2 x 4 KB  [buf][m][k] bf16
  __shared__ unsigned short Bs[2][256 * 32];  // 2 x 16 KB [buf][n][k] bf16
  __shared__ float4 w1s[2][8][8];             // 2 x 1 KB  [buf][q][k4] fp32
  __shared__ float b1s[2048];                 // 8 KB
  // total 50 KB -> 2 blocks/CU (100 KB of 160)

  const int t = threadIdx.x;
  const int lane = t & 63;
  const int w = t >> 6;
  const int mt = (int)(blockIdx.x >> 1);
  const int nt = (int)(blockIdx.x & 1);
  const int r0 = mt * 64;
  const int c0 = nt * 256;

  const int arow = t >> 2;     // 0..63: act row this thread produces
  const int k8 = (t & 3) * 8;  // k-octet within the 32-wide K-step
  const int k4 = (t & 3) * 2;  // float4 index of k8

  // ---- prologue ----
  float z[8];
  {
    const float* xr = x + (size_t)(r0 + arow) * 512;
    float4 x0 = *(const float4*)xr;
    float4 x1 = *(const float4*)(xr + 4);
    float4 ra = *(const float4*)ry;
    float4 rb = *(const float4*)(ry + 4);
    z[0] = __cosf(x0.x) * __cosf(ra.x);
    z[1] = __cosf(x0.y) * __cosf(ra.y);
    z[2] = __cosf(x0.z) * __cosf(ra.z);
    z[3] = __cosf(x0.w) * __cosf(ra.w);
    z[4] = __cosf(x1.x) * __cosf(rb.x);
    z[5] = __cosf(x1.y) * __cosf(rb.y);
    z[6] = __cosf(x1.z) * __cosf(rb.z);
    z[7] = __cosf(x1.w) * __cosf(rb.w);
  }
  {  // b1 -> LDS (512 float4 / 256 thr)
    const float4* bsrc = (const float4*)b1;
    ((float4*)b1s)[t * 2] = bsrc[t * 2];
    ((float4*)b1s)[t * 2 + 1] = bsrc[t * 2 + 1];
  }
  // w1 K-slice staging (64 threads, 1 KB): row-major [32][8] -> q-major [8][32]
  auto w1_stage = [&](int slice, int buf) {
    float4 v = *(const float4*)(w1 + slice * 256 + t * 4);
    float* dst = (float*)&w1s[buf][(t & 1) * 4][0];  // q stride = 32 floats
    const int fl = t >> 1;
    dst[fl] = v.x;
    dst[32 + fl] = v.y;
    dst[64 + fl] = v.z;
    dst[96 + fl] = v.w;
  };
  if (t < 64) w1_stage(0, 0);

  // Bs staging: 1024 chunks of 16 B, thread t -> chunks t + p*256 (p=0..3)
  const unsigned short* gB0 =
      w2b + (size_t)(c0 + (t >> 2)) * 2048 + (t & 3) * 8;
  char* lB0 = (char*)&Bs[0][0] + t * 16;
  auto stage_Bs = [&](int slice, int buf) {
    const unsigned short* g = gB0 + slice * 32;
    char* l = lB0 + buf * 16384;
#pragma unroll
    for (int p = 0; p < 4; ++p)
      async_copy16(g + p * 131072, l + p * 4096);  // 131072 = 64 rows * 2048
  };

  // act compute: 8 elems (row arow, k = slice*32 + k8 + 0..7), fp32, -> bf16
  char* aswr = (char*)&As[0][0] + arow * 64 + k8 * 2;
  auto act = [&](int slice, int buf) {
    const float* bp = b1s + slice * 32 + k8;
    float4 hb0 = *(const float4*)bp;
    float4 hb1 = *(const float4*)(bp + 4);
    float h0 = hb0.x, h1 = hb0.y, h2 = hb0.z, h3 = hb0.w;
    float h4 = hb1.x, h5 = hb1.y, h6 = hb1.z, h7 = hb1.w;
#pragma unroll
    for (int q = 0; q < 8; ++q) {
      float4 wa = w1s[buf][q][k4];
      float4 wb = w1s[buf][q][k4 + 1];
      h0 += z[q] * wa.x; h1 += z[q] * wa.y;
      h2 += z[q] * wa.z; h3 += z[q] * wa.w;
      h4 += z[q] * wb.x; h5 += z[q] * wb.y;
      h6 += z[q] * wb.z; h7 += z[q] * wb.w;
    }
    uint4 pk;
    pk.x = f2bf(fmaxf(h0, 0.f)) | ((unsigned)f2bf(fmaxf(h1, 0.f)) << 16);
    pk.y = f2bf(fmaxf(h2, 0.f)) | ((unsigned)f2bf(fmaxf(h3, 0.f)) << 16);
    pk.z = f2bf(fmaxf(h4, 0.f)) | ((unsigned)f2bf(fmaxf(h5, 0.f)) << 16);
    pk.w = f2bf(fmaxf(h6, 0.f)) | ((unsigned)f2bf(fmaxf(h7, 0.f)) << 16);
    *(uint4*)(aswr + buf * 4096) = pk;
  };

  // ---- prologue pipeline fill ----
  stage_Bs(0, 0);
  __syncthreads();  // b1s/w1s[0] visible; Bs[0] drained (vmcnt 0)
  act(0, 0);        // As[0] = act slice 0
  if (t < 64) w1_stage(1, 1);
  __syncthreads();  // As[0], w1s[1] visible

  // wave tile: 4 waves, 1M x 4N -> each wave 64 rows x 64 cols
  const int wn = w * 64;
  const int fr = lane & 15;
  const int quad = lane >> 4;

  f32x4 acc[4][4];
#pragma unroll
  for (int i = 0; i < 4; ++i)
#pragma unroll
    for (int j = 0; j < 4; ++j) acc[i][j] = (f32x4){0.f, 0.f, 0.f, 0.f};

  const char* asbase = (const char*)&As[0][0] + fr * 64 + quad * 16;
  const char* bsbase = (const char*)&Bs[0][0] + (wn + fr) * 64 + quad * 16;

  // ---- main loop: ONE barrier per K-step ----
  for (int kt = 0; kt < 64; ++kt) {
    const int cur = kt & 1;
    const int nxt = cur ^ 1;
    if (kt < 63) stage_Bs(kt + 1, nxt);  // async, lands by barrier

    s16x8 af[4], bfv[4];
#pragma unroll
    for (int i = 0; i < 4; ++i)
      af[i] = *(const s16x8*)(asbase + cur * 4096 + i * 1024);
#pragma unroll
    for (int j = 0; j < 4; ++j)
      bfv[j] = *(const s16x8*)(bsbase + cur * 16384 + j * 1024);

    if (kt < 63) {
      act(kt + 1, nxt);                          // VALU, overlaps MFMA issue
      if (t < 64 && kt < 62) w1_stage(kt + 2, cur);
    }

#pragma unroll
    for (int i = 0; i < 4; ++i)
#pragma unroll
      for (int j = 0; j < 4; ++j)
        acc[i][j] = __builtin_amdgcn_mfma_f32_16x16x32_bf16(af[i], bfv[j],
                                                            acc[i][j], 0, 0, 0);
    __syncthreads();  // readers of [cur] done; [nxt] staging/act complete
  }

  // epilogue: C/D layout col = lane&15, row = quad*4 + reg (m89/m91 verified)
  float bias[4];
#pragma unroll
  for (int j = 0; j < 4; ++j) bias[j] = b2[c0 + wn + j * 16 + fr];
#pragma unroll
  for (int i = 0; i < 4; ++i) {
    const int rbase = r0 + i * 16 + quad * 4;
#pragma unroll
    for (int rr = 0; rr < 4; ++rr) {
      float* crow = C + (size_t)(rbase + rr) * 512;
#pragma unroll
      for (int j = 0; j < 4; ++j)
        crow[c0 + wn + j * 16 + fr] = acc[i][j][rr] + bias[j];
    }
  }
}

// ---------------------------------------------------------------------------
// Emergency fallback (only if ws_size is tiny): fully fused fp32, 1 row/block.
// ---------------------------------------------------------------------------
__global__ __launch_bounds__(256) void k_naive(
    const float* __restrict__ x, const float* __restrict__ ry,
    const float* __restrict__ w1, const float* __restrict__ b1,
    const float* __restrict__ w2, const float* __restrict__ b2,
    float* __restrict__ out) {
  __shared__ float zsh[8];
  __shared__ float acts[2048];
  const int r = blockIdx.x;
  const int t = threadIdx.x;
  if (t < 8) zsh[t] = __cosf(x[(size_t)r * 512 + t]) * __cosf(ry[t]);
  __syncthreads();
  float z[8];
#pragma unroll
  for (int q = 0; q < 8; ++q) z[q] = zsh[q];
#pragma unroll
  for (int i = 0; i < 8; ++i) {
    const int f = t * 8 + i;
    const float* wr = w1 + (size_t)f * 8;
    float4 a = *(const float4*)wr;
    float4 b = *(const float4*)(wr + 4);
    float h = b1[f] + z[0] * a.x + z[1] * a.y + z[2] * a.z + z[3] * a.w +
              z[4] * b.x + z[5] * b.y + z[6] * b.z + z[7] * b.w;
    acts[f] = fmaxf(h, 0.0f);
  }
  __syncthreads();
  for (int ee = 0; ee < 2; ++ee) {
    const int e = t + ee * 256;
    const float* wr = w2 + (size_t)e * 2048;
    float acc = b2[e];
    for (int f = 0; f < 2048; f += 4) {
      float4 wv = *(const float4*)(wr + f);
      float4 av = *(const float4*)(acts + f);
      acc += av.x * wv.x + av.y * wv.y + av.z * wv.z + av.w * wv.w;
    }
    out[(size_t)r * 512 + e] = acc;
  }
}

extern "C" void kernel_launch(void* const* d_in, const int* in_sizes, int n_in,
                              void* d_out, int out_size, void* d_ws,
                              size_t ws_size, hipStream_t stream) {
  const float* x  = (const float*)d_in[0];
  const float* ry = (const float*)d_in[1];
  const float* w1 = (const float*)d_in[2];
  const float* b1 = (const float*)d_in[3];
  const float* w2 = (const float*)d_in[4];
  const float* b2 = (const float*)d_in[5];
  float* out = (float*)d_out;

  const size_t w2b_bytes = (size_t)512 * 2048 * 2;  // 2 MB bf16 w2
  if (ws_size < w2b_bytes) {
    k_naive<<<dim3(16384), dim3(256), 0, stream>>>(x, ry, w1, b1, w2, b2, out);
    return;
  }
  unsigned short* w2b = (unsigned short*)d_ws;
  k_w2<<<dim3(1024), dim3(256), 0, stream>>>(w2, w2b);
  k_fused<<<dim3(512), dim3(256), 0, stream>>>(x, ry, w1, b1, w2b, b2, out);
}

// Round 3
// 151.273 us; speedup vs baseline: 1.1966x; 1.1966x over previous
//
#include <hip/hip_runtime.h>
#include <cstdint>
#include <cstddef>

// Problem: B=8,S=2048,E=512,FFN=2048,Q=8 -> M=16384, K=2048, N=512.
// Round-3 structure: BM=128, BN=256, 512 thr (8 waves, 2Mx4N wave tiles),
// grid=256 (1 block/CU). Whole w1 (64 KB) + b1 (8 KB) resident in LDS.
// Counted-vmcnt pipeline (T4): raw s_barrier + s_waitcnt vmcnt(2) -- the
// next Bs slice's 2 global_load_lds stay in flight across both barriers.
// act computed per K-step: thread owns 2 f-cols x 4 rows; z (4x8) in regs.

typedef __attribute__((ext_vector_type(8))) short s16x8;
typedef __attribute__((ext_vector_type(4))) float f32x4;

__device__ __forceinline__ unsigned short f2bf(float f) {
  unsigned int u = __float_as_uint(f);
  unsigned int r = u + 0x7fffu + ((u >> 16) & 1u);
  return (unsigned short)(r >> 16);
}

__device__ __forceinline__ void async_copy16(const void* g, void* l) {
  __builtin_amdgcn_global_load_lds(
      (const __attribute__((address_space(1))) void*)(uintptr_t)g,
      (__attribute__((address_space(3))) void*)(unsigned int)(uintptr_t)l,
      16, 0, 0);
}

// ---------------------------------------------------------------------------
// Kernel 1: w2 (fp32 [512][2048]) -> bf16 same layout
// ---------------------------------------------------------------------------
__global__ __launch_bounds__(256) void k_w2(const float* __restrict__ w2,
                                            unsigned short* __restrict__ w2b) {
  size_t i = ((size_t)blockIdx.x * 256 + threadIdx.x) * 4;
  float4 v = *(const float4*)(w2 + i);
  uint2 p;
  p.x = f2bf(v.x) | ((unsigned)f2bf(v.y) << 16);
  p.y = f2bf(v.z) | ((unsigned)f2bf(v.w) << 16);
  *(uint2*)(w2b + i) = p;
}

// ---------------------------------------------------------------------------
// Kernel 2 (fused): C[m][n] = sum_k relu(z[m]·w1[k]+b1[k]) * w2b[n][k] + b2[n]
// ---------------------------------------------------------------------------
__global__ __launch_bounds__(512, 2) void k_fused(
    const float* __restrict__ x, const float* __restrict__ ry,
    const float* __restrict__ w1, const float* __restrict__ b1,
    const unsigned short* __restrict__ w2b, const float* __restrict__ b2,
    float* __restrict__ C) {
  __shared__ unsigned short As[2][128 * 32];  // 16 KB [buf][m][k]
  __shared__ unsigned short Bs[2][256 * 32];  // 32 KB [buf][n][k]
  __shared__ float w1s[2048 * 8];             // 64 KB, f-major [f][q]
  __shared__ float b1s[2048];                 // 8 KB   -> 120 KB total

  const int t = threadIdx.x;
  const int lane = t & 63;
  const int w = t >> 6;
  const int mt = (int)(blockIdx.x >> 1);
  const int nt = (int)(blockIdx.x & 1);
  const int r0 = mt * 128;
  const int c0 = nt * 256;
  const int fp = t & 15;  // f-pair index within 32-wide K-step
  const int rq = t >> 4;  // row-quad: rows rq*4 .. rq*4+3

  // ---- prologue: issue ALL staging, then one vmcnt(0) drain ----
  const unsigned short* gB =
      w2b + (size_t)(c0 + (t >> 2)) * 2048 + (t & 3) * 8;
  char* lB = (char*)Bs + t * 16;
  // Bs slice 0 -> buf0 (2 chunks/thread)
  async_copy16(gB, lB);
  async_copy16(gB + (size_t)128 * 2048, lB + 8192);
  // w1s: 64 KB = 4096 chunks, 8/thread (f-major layout preserved)
#pragma unroll
  for (int i = 0; i < 8; ++i)
    async_copy16(w1 + ((size_t)t + i * 512) * 4,
                 (char*)w1s + ((size_t)t + i * 512) * 16);
  // b1s: 512 chunks
  async_copy16(b1 + (size_t)t * 4, (char*)b1s + (size_t)t * 16);
  // Bs slice 1 -> buf1
  async_copy16(gB + 32, lB + 16384);
  async_copy16(gB + 32 + (size_t)128 * 2048, lB + 16384 + 8192);

  // z for this thread's 4 rows (hoisted for the whole K-loop)
  float zr[4][8];
  {
    float4 ra = *(const float4*)ry;
    float4 rb = *(const float4*)(ry + 4);
    float cy[8] = {__cosf(ra.x), __cosf(ra.y), __cosf(ra.z), __cosf(ra.w),
                   __cosf(rb.x), __cosf(rb.y), __cosf(rb.z), __cosf(rb.w)};
#pragma unroll
    for (int r = 0; r < 4; ++r) {
      const float* xr = x + (size_t)(r0 + rq * 4 + r) * 512;
      float4 x0 = *(const float4*)xr;
      float4 x1 = *(const float4*)(xr + 4);
      zr[r][0] = __cosf(x0.x) * cy[0];
      zr[r][1] = __cosf(x0.y) * cy[1];
      zr[r][2] = __cosf(x0.z) * cy[2];
      zr[r][3] = __cosf(x0.w) * cy[3];
      zr[r][4] = __cosf(x1.x) * cy[4];
      zr[r][5] = __cosf(x1.y) * cy[5];
      zr[r][6] = __cosf(x1.z) * cy[6];
      zr[r][7] = __cosf(x1.w) * cy[7];
    }
  }

  asm volatile("s_waitcnt vmcnt(0) lgkmcnt(0)" ::: "memory");
  __builtin_amdgcn_sched_barrier(0);
  __builtin_amdgcn_s_barrier();

  // act: 2 f-cols x 4 rows -> 8 bf16 into As[buf]. fp32 chain identical to
  // previous passing rounds; v_cvt_pk_bf16_f32 is the same RTNE rounding.
  char* aswr = (char*)As + (size_t)rq * 4 * 64 + fp * 4;
  auto act = [&](int s, int b) {
    const float* wrow = w1s + ((size_t)s * 32 + fp * 2) * 8;
    f32x4 v0 = *(const f32x4*)(wrow);       // w1[F0][0..3]
    f32x4 v1 = *(const f32x4*)(wrow + 4);   // w1[F0][4..7]
    f32x4 v2 = *(const f32x4*)(wrow + 8);   // w1[F1][0..3]
    f32x4 v3 = *(const f32x4*)(wrow + 12);  // w1[F1][4..7]
    float b0 = b1s[s * 32 + fp * 2];
    float b1v = b1s[s * 32 + fp * 2 + 1];
    char* dst = aswr + b * 8192;
#pragma unroll
    for (int r = 0; r < 4; ++r) {
      float h0 = b0, h1 = b1v;
      h0 += zr[r][0] * v0[0]; h1 += zr[r][0] * v2[0];
      h0 += zr[r][1] * v0[1]; h1 += zr[r][1] * v2[1];
      h0 += zr[r][2] * v0[2]; h1 += zr[r][2] * v2[2];
      h0 += zr[r][3] * v0[3]; h1 += zr[r][3] * v2[3];
      h0 += zr[r][4] * v1[0]; h1 += zr[r][4] * v3[0];
      h0 += zr[r][5] * v1[1]; h1 += zr[r][5] * v3[1];
      h0 += zr[r][6] * v1[2]; h1 += zr[r][6] * v3[2];
      h0 += zr[r][7] * v1[3]; h1 += zr[r][7] * v3[3];
      h0 = fmaxf(h0, 0.0f);
      h1 = fmaxf(h1, 0.0f);
      unsigned int u;
      asm("v_cvt_pk_bf16_f32 %0, %1, %2" : "=v"(u) : "v"(h0), "v"(h1));
      *(unsigned int*)(dst + r * 64) = u;
    }
  };

  act(0, 0);  // As[0] = act slice 0 (made visible by iter-0's barrier)

  // wave tiles: 8 waves = 2M x 4N, each 64x64
  const int wm = (w >> 2) * 64;
  const int wn = (w & 3) * 64;
  const int fr = lane & 15;
  const int quad = lane >> 4;

  f32x4 acc[4][4];
#pragma unroll
  for (int i = 0; i < 4; ++i)
#pragma unroll
    for (int j = 0; j < 4; ++j) acc[i][j] = (f32x4){0.f, 0.f, 0.f, 0.f};

  const char* pAb = (const char*)As + (size_t)(wm + fr) * 64 + quad * 16;
  const char* pBb = (const char*)Bs + (size_t)(wn + fr) * 64 + quad * 16;

  for (int kt = 0; kt < 64; ++kt) {
    const int cur = kt & 1;

    // (C) Bs[cur] ready (2 newest loads = slice kt+1 stay in flight),
    //     As[cur] act-writes visible.
    asm volatile("s_waitcnt vmcnt(2) lgkmcnt(0)" ::: "memory");
    __builtin_amdgcn_sched_barrier(0);
    __builtin_amdgcn_s_barrier();

    // (D) frag reads + act(kt+1) + MFMA(kt), compiler-interleaved
    s16x8 af[4], bfv[4];
    const char* pA = pAb + cur * 8192;
    const char* pB = pBb + cur * 16384;
#pragma unroll
    for (int i = 0; i < 4; ++i) af[i] = *(const s16x8*)(pA + i * 1024);
#pragma unroll
    for (int j = 0; j < 4; ++j) bfv[j] = *(const s16x8*)(pB + j * 1024);

    if (kt < 63) act(kt + 1, cur ^ 1);

#pragma unroll
    for (int i = 0; i < 4; ++i)
#pragma unroll
      for (int j = 0; j < 4; ++j)
        acc[i][j] = __builtin_amdgcn_mfma_f32_16x16x32_bf16(af[i], bfv[j],
                                                            acc[i][j], 0, 0, 0);

    // (E) all LDS reads/writes of this iter retired -> safe to overwrite
    asm volatile("s_waitcnt lgkmcnt(0)" ::: "memory");
    __builtin_amdgcn_sched_barrier(0);
    __builtin_amdgcn_s_barrier();

    // (A) stage slice kt+2 into buf[cur] (just-freed). Never drained to 0.
    if (kt < 62) {
      const unsigned short* g = gB + (kt + 2) * 32;
      char* l = lB + cur * 16384;
      async_copy16(g, l);
      async_copy16(g + (size_t)128 * 2048, l + 8192);
    }
  }

  // epilogue: C/D layout col = lane&15, row = quad*4 + reg (m89/m91 verified)
  float bias[4];
#pragma unroll
  for (int j = 0; j < 4; ++j) bias[j] = b2[c0 + wn + j * 16 + fr];
#pragma unroll
  for (int i = 0; i < 4; ++i) {
    const int rbase = r0 + wm + i * 16 + quad * 4;
#pragma unroll
    for (int rr = 0; rr < 4; ++rr) {
      float* crow = C + (size_t)(rbase + rr) * 512;
#pragma unroll
      for (int j = 0; j < 4; ++j)
        crow[c0 + wn + j * 16 + fr] = acc[i][j][rr] + bias[j];
    }
  }
}

// ---------------------------------------------------------------------------
// Emergency fallback (only if ws_size is tiny): fully fused fp32, 1 row/block.
// ---------------------------------------------------------------------------
__global__ __launch_bounds__(256) void k_naive(
    const float* __restrict__ x, const float* __restrict__ ry,
    const float* __restrict__ w1, const float* __restrict__ b1,
    const float* __restrict__ w2, const float* __restrict__ b2,
    float* __restrict__ out) {
  __shared__ float zsh[8];
  __shared__ float acts[2048];
  const int r = blockIdx.x;
  const int t = threadIdx.x;
  if (t < 8) zsh[t] = __cosf(x[(size_t)r * 512 + t]) * __cosf(ry[t]);
  __syncthreads();
  float z[8];
#pragma unroll
  for (int q = 0; q < 8; ++q) z[q] = zsh[q];
#pragma unroll
  for (int i = 0; i < 8; ++i) {
    const int f = t * 8 + i;
    const float* wr = w1 + (size_t)f * 8;
    float4 a = *(const float4*)wr;
    float4 b = *(const float4*)(wr + 4);
    float h = b1[f] + z[0] * a.x + z[1] * a.y + z[2] * a.z + z[3] * a.w +
              z[4] * b.x + z[5] * b.y + z[6] * b.z + z[7] * b.w;
    acts[f] = fmaxf(h, 0.0f);
  }
  __syncthreads();
  for (int ee = 0; ee < 2; ++ee) {
    const int e = t + ee * 256;
    const float* wr = w2 + (size_t)e * 2048;
    float acc = b2[e];
    for (int f = 0; f < 2048; f += 4) {
      float4 wv = *(const float4*)(wr + f);
      float4 av = *(const float4*)(acts + f);
      acc += av.x * wv.x + av.y * wv.y + av.z * wv.z + av.w * wv.w;
    }
    out[(size_t)r * 512 + e] = acc;
  }
}

extern "C" void kernel_launch(void* const* d_in, const int* in_sizes, int n_in,
                              void* d_out, int out_size, void* d_ws,
                              size_t ws_size, hipStream_t stream) {
  const float* x  = (const float*)d_in[0];
  const float* ry = (const float*)d_in[1];
  const float* w1 = (const float*)d_in[2];
  const float* b1 = (const float*)d_in[3];
  const float* w2 = (const float*)d_in[4];
  const float* b2 = (const float*)d_in[5];
  float* out = (float*)d_out;

  const size_t w2b_bytes = (size_t)512 * 2048 * 2;  // 2 MB bf16 w2
  if (ws_size < w2b_bytes) {
    k_naive<<<dim3(16384), dim3(256), 0, stream>>>(x, ry, w1, b1, w2, b2, out);
    return;
  }
  unsigned short* w2b = (unsigned short*)d_ws;
  k_w2<<<dim3(1024), dim3(256), 0, stream>>>(w2, w2b);
  k_fused<<<dim3(256), dim3(512), 0, stream>>>(x, ry, w1, b1, w2b, b2, out);
}

// Round 4
// 148.275 us; speedup vs baseline: 1.2208x; 1.0202x over previous
//
#include <hip/hip_runtime.h>
#include <cstdint>
#include <cstddef>

// Problem: B=8,S=2048,E=512,FFN=2048,Q=8 -> M=16384, K=2048, N=512.
// Round-4: same pipeline as round 3 (BM=128,BN=256,512thr,1 blk/CU, whole w1
// in LDS, counted-vmcnt double-buffer) but ALL LDS layouts are conflict-free
// images:
//  - Bs: staged from a pre-permuted w2b image (k_w2 builds it) so the MFMA
//    B-frag b128 read is lane-linear (addr = lane*16 mod 1024) = bank floor.
//  - As: slot-permuted image; act's b32 writes are 2 lanes/bank (free) and
//    A-frag reads hit the b128 floor.
//  - w1s: chunk-swizzled image via per-lane staging source; act's 4 b128
//    reads become fp*16-linear (conflict-free).

typedef __attribute__((ext_vector_type(8))) short s16x8;
typedef __attribute__((ext_vector_type(4))) float f32x4;

__device__ __forceinline__ unsigned short f2bf(float f) {
  unsigned int u = __float_as_uint(f);
  unsigned int r = u + 0x7fffu + ((u >> 16) & 1u);
  return (unsigned short)(r >> 16);
}

__device__ __forceinline__ void async_copy16(const void* g, void* l) {
  __builtin_amdgcn_global_load_lds(
      (const __attribute__((address_space(1))) void*)(uintptr_t)g,
      (__attribute__((address_space(3))) void*)(unsigned int)(uintptr_t)l,
      16, 0, 0);
}

// ---------------------------------------------------------------------------
// Kernel 1: build w2b image. Layout: [nt(2)][slice s(64)][chunk ci(1024)]x16B
// where ci = nhi*64 + quad*16 + nlo  (n_local = nhi*16+nlo in 0..255,
// n_global = nt*256+n_local, data = bf16(w2[n_global][s*32+quad*8 .. +7])).
// Staging then reads contiguous 16-KB slices; B-frag LDS reads are linear.
// ---------------------------------------------------------------------------
__global__ __launch_bounds__(256) void k_w2(const float* __restrict__ w2,
                                            unsigned short* __restrict__ img) {
  const int n = blockIdx.x;   // 0..511
  const int t = threadIdx.x;  // s = t>>2, quad = t&3
  const int s = t >> 2, quad = t & 3;
  const float* src = w2 + (size_t)n * 2048 + t * 8;  // coalesced
  float4 a = *(const float4*)src;
  float4 b = *(const float4*)(src + 4);
  uint4 pk;
  pk.x = f2bf(a.x) | ((unsigned)f2bf(a.y) << 16);
  pk.y = f2bf(a.z) | ((unsigned)f2bf(a.w) << 16);
  pk.z = f2bf(b.x) | ((unsigned)f2bf(b.y) << 16);
  pk.w = f2bf(b.z) | ((unsigned)f2bf(b.w) << 16);
  const int nt = n >> 8, nl = n & 255, nhi = nl >> 4, nlo = nl & 15;
  const size_t ci = (size_t)(nt * 64 + s) * 1024 + nhi * 64 + quad * 16 + nlo;
  *(uint4*)(img + ci * 8) = pk;
}

// ---------------------------------------------------------------------------
// Kernel 2 (fused): C[m][n] = sum_k relu(z[m]·w1[k]+b1[k]) * w2[n][k] + b2[n]
// ---------------------------------------------------------------------------
__global__ __launch_bounds__(512, 2) void k_fused(
    const float* __restrict__ x, const float* __restrict__ ry,
    const float* __restrict__ w1, const float* __restrict__ b1,
    const unsigned short* __restrict__ w2b, const float* __restrict__ b2,
    float* __restrict__ C) {
  __shared__ unsigned short As[2][128 * 32];  // 16 KB slot-permuted image
  __shared__ unsigned short Bs[2][256 * 32];  // 32 KB linear-frag image
  __shared__ float w1s[2048 * 8];             // 64 KB chunk-swizzled image
  __shared__ float b1s[2048];                 // 8 KB  -> 120 KB total

  const int t = threadIdx.x;
  const int lane = t & 63;
  const int w = t >> 6;
  const int mt = (int)(blockIdx.x >> 1);
  const int nt = (int)(blockIdx.x & 1);
  const int r0 = mt * 128;
  const int c0 = nt * 256;
  const int fp = t & 15;  // f-pair index within 32-wide K-step
  const int rq = t >> 4;  // row-quad: rows rq*4 .. rq*4+3

  // ---- prologue: issue all staging, then one vmcnt(0) drain ----
  const unsigned short* gB = w2b + (size_t)nt * 64 * 8192 + t * 8;
  char* lB = (char*)Bs + t * 16;
  // Bs slice 0 -> buf0, slice 1 -> buf1 (2 chunks/thread each, contiguous src)
  async_copy16(gB, lB);
  async_copy16(gB + 4096, lB + 8192);
  // w1s image: 4096 chunks, 8/thread; per-lane swizzled SOURCE, linear dest.
  // LDS chunk l (block s=l>>6, wsl=l&63): idx = ((wsl&15)<<2)|(wsl>>4),
  // f = s*32 + (idx>>1), half = idx&1 -> src = w1 + f*8 + half*4 floats.
#pragma unroll
  for (int i = 0; i < 8; ++i) {
    const int l = t + i * 512;
    const int sl = l >> 6, wsl = l & 63;
    const int idx = ((wsl & 15) << 2) | (wsl >> 4);
    async_copy16(w1 + (size_t)(sl * 32 + (idx >> 1)) * 8 + (idx & 1) * 4,
                 (char*)w1s + (size_t)l * 16);
  }
  // b1s linear
  async_copy16(b1 + (size_t)t * 4, (char*)b1s + (size_t)t * 16);
  // Bs slice 1 -> buf1
  async_copy16(gB + 8192, lB + 16384);
  async_copy16(gB + 8192 + 4096, lB + 16384 + 8192);

  // z for this thread's 4 rows (whole K-loop in regs)
  float zr[4][8];
  {
    float4 ra = *(const float4*)ry;
    float4 rb = *(const float4*)(ry + 4);
    float cy[8] = {__cosf(ra.x), __cosf(ra.y), __cosf(ra.z), __cosf(ra.w),
                   __cosf(rb.x), __cosf(rb.y), __cosf(rb.z), __cosf(rb.w)};
#pragma unroll
    for (int r = 0; r < 4; ++r) {
      const float* xr = x + (size_t)(r0 + rq * 4 + r) * 512;
      float4 x0 = *(const float4*)xr;
      float4 x1 = *(const float4*)(xr + 4);
      zr[r][0] = __cosf(x0.x) * cy[0];
      zr[r][1] = __cosf(x0.y) * cy[1];
      zr[r][2] = __cosf(x0.z) * cy[2];
      zr[r][3] = __cosf(x0.w) * cy[3];
      zr[r][4] = __cosf(x1.x) * cy[4];
      zr[r][5] = __cosf(x1.y) * cy[5];
      zr[r][6] = __cosf(x1.z) * cy[6];
      zr[r][7] = __cosf(x1.w) * cy[7];
    }
  }

  asm volatile("s_waitcnt vmcnt(0) lgkmcnt(0)" ::: "memory");
  __builtin_amdgcn_sched_barrier(0);
  __builtin_amdgcn_s_barrier();

  // As image slot (bijective): slot(q, r15) = (r15&3)<<4 | (q>>1)<<3 |
  // (r15>>2)<<1 | (q&1).  Write side (thread rq,fp; row r15 = (rq&3)*4+i,
  // q = fp>>2): bank = lq,fp2,fp1,fp0 -> 2 lanes/bank (free).
  char* aswr = (char*)As + (rq >> 2) * 1024 +
               (((((fp >> 3) & 1) << 3) | ((rq & 3) << 1) | ((fp >> 2) & 1)) << 4) +
               (fp & 3) * 4;
  // act: 2 f-cols x 4 rows. w1s reads are fp*16-linear per b128 (swizzled
  // image). fp32 chain + RTNE cvt identical to previous passing rounds.
  auto act = [&](int s, int b) {
    const char* wb = (const char*)w1s + s * 1024 + fp * 16;
    f32x4 v0 = *(const f32x4*)(wb);        // w1[F0][0..3]
    f32x4 v1 = *(const f32x4*)(wb + 256);  // w1[F0][4..7]
    f32x4 v2 = *(const f32x4*)(wb + 512);  // w1[F1][0..3]
    f32x4 v3 = *(const f32x4*)(wb + 768);  // w1[F1][4..7]
    float b0 = b1s[s * 32 + fp * 2];
    float b1v = b1s[s * 32 + fp * 2 + 1];
    char* dst = aswr + b * 8192;
#pragma unroll
    for (int r = 0; r < 4; ++r) {
      float h0 = b0, h1 = b1v;
      h0 += zr[r][0] * v0[0]; h1 += zr[r][0] * v2[0];
      h0 += zr[r][1] * v0[1]; h1 += zr[r][1] * v2[1];
      h0 += zr[r][2] * v0[2]; h1 += zr[r][2] * v2[2];
      h0 += zr[r][3] * v0[3]; h1 += zr[r][3] * v2[3];
      h0 += zr[r][4] * v1[0]; h1 += zr[r][4] * v3[0];
      h0 += zr[r][5] * v1[1]; h1 += zr[r][5] * v3[1];
      h0 += zr[r][6] * v1[2]; h1 += zr[r][6] * v3[2];
      h0 += zr[r][7] * v1[3]; h1 += zr[r][7] * v3[3];
      h0 = fmaxf(h0, 0.0f);
      h1 = fmaxf(h1, 0.0f);
      unsigned int u;
      asm("v_cvt_pk_bf16_f32 %0, %1, %2" : "=v"(u) : "v"(h0), "v"(h1));
      *(unsigned int*)(dst + r * 256) = u;  // slot bit4 = row&3 -> +256 B
    }
  };

  act(0, 0);  // As[0] = act slice 0 (visible after iter-0 barrier)

  // wave tiles: 8 waves = 2M x 4N, each 64x64
  const int wm = (w >> 2) * 64;
  const int wn = (w & 3) * 64;
  const int fr = lane & 15;
  const int quad = lane >> 4;

  f32x4 acc[4][4];
#pragma unroll
  for (int i = 0; i < 4; ++i)
#pragma unroll
    for (int j = 0; j < 4; ++j) acc[i][j] = (f32x4){0.f, 0.f, 0.f, 0.f};

  // frag pointers into the images
  const int slotA = ((fr & 3) << 4) | (((quad >> 1) & 1) << 3) |
                    ((fr >> 2) << 1) | (quad & 1);
  const char* pAb = (const char*)As + ((wm >> 4) * 1024) + slotA * 16;
  const char* pBb = (const char*)Bs + ((wn >> 4) * 1024) + quad * 256 + fr * 16;

  for (int kt = 0; kt < 64; ++kt) {
    const int cur = kt & 1;

    // (C) Bs[cur] ready (2 newest loads = slice kt+1 stay in flight),
    //     As[cur] act-writes visible.
    asm volatile("s_waitcnt vmcnt(2) lgkmcnt(0)" ::: "memory");
    __builtin_amdgcn_sched_barrier(0);
    __builtin_amdgcn_s_barrier();

    // (D) frag reads + act(kt+1) + MFMA(kt)
    s16x8 af[4], bfv[4];
    const char* pA = pAb + cur * 8192;
    const char* pB = pBb + cur * 16384;
#pragma unroll
    for (int i = 0; i < 4; ++i) af[i] = *(const s16x8*)(pA + i * 1024);
#pragma unroll
    for (int j = 0; j < 4; ++j) bfv[j] = *(const s16x8*)(pB + j * 1024);

    if (kt < 63) act(kt + 1, cur ^ 1);

    __builtin_amdgcn_s_setprio(1);
#pragma unroll
    for (int i = 0; i < 4; ++i)
#pragma unroll
      for (int j = 0; j < 4; ++j)
        acc[i][j] = __builtin_amdgcn_mfma_f32_16x16x32_bf16(af[i], bfv[j],
                                                            acc[i][j], 0, 0, 0);
    __builtin_amdgcn_s_setprio(0);

    // (E) all LDS ops of this iter retired -> safe to overwrite
    asm volatile("s_waitcnt lgkmcnt(0)" ::: "memory");
    __builtin_amdgcn_sched_barrier(0);
    __builtin_amdgcn_s_barrier();

    // (A) stage slice kt+2 into buf[cur] (just freed). Never drained to 0.
    if (kt < 62) {
      const unsigned short* g = gB + (size_t)(kt + 2) * 8192;
      char* l = lB + cur * 16384;
      async_copy16(g, l);
      async_copy16(g + 4096, l + 8192);
    }
  }

  // epilogue: C/D layout col = lane&15, row = quad*4 + reg (m89/m91 verified)
  float bias[4];
#pragma unroll
  for (int j = 0; j < 4; ++j) bias[j] = b2[c0 + wn + j * 16 + fr];
#pragma unroll
  for (int i = 0; i < 4; ++i) {
    const int rbase = r0 + wm + i * 16 + quad * 4;
#pragma unroll
    for (int rr = 0; rr < 4; ++rr) {
      float* crow = C + (size_t)(rbase + rr) * 512;
#pragma unroll
      for (int j = 0; j < 4; ++j)
        crow[c0 + wn + j * 16 + fr] = acc[i][j][rr] + bias[j];
    }
  }
}

// ---------------------------------------------------------------------------
// Emergency fallback (only if ws_size is tiny): fully fused fp32, 1 row/block.
// ---------------------------------------------------------------------------
__global__ __launch_bounds__(256) void k_naive(
    const float* __restrict__ x, const float* __restrict__ ry,
    const float* __restrict__ w1, const float* __restrict__ b1,
    const float* __restrict__ w2, const float* __restrict__ b2,
    float* __restrict__ out) {
  __shared__ float zsh[8];
  __shared__ float acts[2048];
  const int r = blockIdx.x;
  const int t = threadIdx.x;
  if (t < 8) zsh[t] = __cosf(x[(size_t)r * 512 + t]) * __cosf(ry[t]);
  __syncthreads();
  float z[8];
#pragma unroll
  for (int q = 0; q < 8; ++q) z[q] = zsh[q];
#pragma unroll
  for (int i = 0; i < 8; ++i) {
    const int f = t * 8 + i;
    const float* wr = w1 + (size_t)f * 8;
    float4 a = *(const float4*)wr;
    float4 b = *(const float4*)(wr + 4);
    float h = b1[f] + z[0] * a.x + z[1] * a.y + z[2] * a.z + z[3] * a.w +
              z[4] * b.x + z[5] * b.y + z[6] * b.z + z[7] * b.w;
    acts[f] = fmaxf(h, 0.0f);
  }
  __syncthreads();
  for (int ee = 0; ee < 2; ++ee) {
    const int e = t + ee * 256;
    const float* wr = w2 + (size_t)e * 2048;
    float acc = b2[e];
    for (int f = 0; f < 2048; f += 4) {
      float4 wv = *(const float4*)(wr + f);
      float4 av = *(const float4*)(acts + f);
      acc += av.x * wv.x + av.y * wv.y + av.z * wv.z + av.w * wv.w;
    }
    out[(size_t)r * 512 + e] = acc;
  }
}

extern "C" void kernel_launch(void* const* d_in, const int* in_sizes, int n_in,
                              void* d_out, int out_size, void* d_ws,
                              size_t ws_size, hipStream_t stream) {
  const float* x  = (const float*)d_in[0];
  const float* ry = (const float*)d_in[1];
  const float* w1 = (const float*)d_in[2];
  const float* b1 = (const float*)d_in[3];
  const float* w2 = (const float*)d_in[4];
  const float* b2 = (const float*)d_in[5];
  float* out = (float*)d_out;

  const size_t w2b_bytes = (size_t)512 * 2048 * 2;  // 2 MB bf16 w2 image
  if (ws_size < w2b_bytes) {
    k_naive<<<dim3(16384), dim3(256), 0, stream>>>(x, ry, w1, b1, w2, b2, out);
    return;
  }
  unsigned short* w2b = (unsigned short*)d_ws;
  k_w2<<<dim3(512), dim3(256), 0, stream>>>(w2, w2b);
  k_fused<<<dim3(256), dim3(512), 0, stream>>>(x, ry, w1, b1, w2b, b2, out);
}